// Round 15
// baseline (101.108 us; speedup 1.0000x reference)
//
#include <hip/hip_runtime.h>
#include <hip/hip_bf16.h>

#define VOCAB 50000
#define HID   256
#define BATCH 512
#define GH    768   // 3*H

typedef __attribute__((ext_vector_type(8)))  __bf16 bf16x8;
typedef __attribute__((ext_vector_type(4)))  float  f32x4;
typedef __attribute__((ext_vector_type(16))) float  f32x16;
typedef __attribute__((ext_vector_type(4)))  unsigned int u32x4;

union BFrag {
    bf16x8 v;
    u32x4  q;
    __bf16 b[8];
};

__device__ __forceinline__ float fast_sigmoid(float x) {
    return 1.0f / (1.0f + __expf(-x));
}
__device__ __forceinline__ float fast_tanh(float x) {
    return 1.0f - 2.0f / (1.0f + __expf(2.0f * x));
}

// 8 consecutive f32 -> one bf16x8 fragment via native casts.
__device__ __forceinline__ void cvt8(BFrag& t, f32x4 lo, f32x4 hi) {
    t.b[0] = (__bf16)lo.x; t.b[1] = (__bf16)lo.y;
    t.b[2] = (__bf16)lo.z; t.b[3] = (__bf16)lo.w;
    t.b[4] = (__bf16)hi.x; t.b[5] = (__bf16)hi.y;
    t.b[6] = (__bf16)hi.z; t.b[7] = (__bf16)hi.w;
}

// K3: logit = tanh(h1 @ w_out^T + b_out), 32x32x16 MFMA, swapped operands,
// 32 cols/wave (HALVES total LDS reads vs 16 cols/wave: every wave must
// ingest all of A; wider col coverage = fewer col-waves).
// Skeleton = R8 (best, 61.2us): one block per 64-col tile (w_out fetched
// exactly once, NT), 64-row chunks, SINGLE 32KB swizzled LDS buffer, raw
// s_barrier pair per chunk, stores never drained in-loop.
// Waves 2x2: wc = col-half (32 cols), wr = row-half (32 rows of the chunk).
// w_out = MFMA A-operand (16 frags, 64 VGPR, pinned); h1 = B-operand from
// LDS (16 ds_read_b128 per chunk-wave, conflict-free under the swizzle).
// D: row=vocab col=(reg&3)+8*(reg>>2)+4*(lane>>5), col=batch row=lane&31
// -> 4 x dwordx4 stores per thread per chunk. launch_bounds(256,3): VGPR
// cap 170 (est ~150, no spill), 3 blocks/CU x 4 waves = 12 waves/CU.
__global__ __launch_bounds__(256, 3) void gemm_swp32(
    const unsigned short* __restrict__ Abf, const float* __restrict__ Bm,
    float* __restrict__ C, const float* __restrict__ bias, int mChunks)
{
    __shared__ char ldsA[64 * 512];           // 64 rows x 256 bf16, swizzled

    const int tid  = threadIdx.x;
    const int wid  = tid >> 6;
    const int lane = tid & 63;
    const int cl   = lane & 31;               // w_out row / batch row index
    const int h    = lane >> 5;               // k-half
    const int wc   = wid & 1;                 // col half of 64-col tile
    const int wr   = wid >> 1;                // row half of 64-row chunk

    const int colwave = blockIdx.x * 64 + wc * 32;
    const int wcol    = colwave + cl;
    const int bw      = wcol < VOCAB ? wcol : (VOCAB - 1);

    // ---- w_out fragments: 16 (64 VGPR), NT load + convert once, pin ----
    BFrag bf[16];
    {
        const f32x4* wrow = reinterpret_cast<const f32x4*>(Bm + (size_t)bw * 256);
        #pragma unroll
        for (int ks = 0; ks < 16; ks++) {
            f32x4 lo = __builtin_nontemporal_load(&wrow[ks * 4 + h * 2]);
            f32x4 hi = __builtin_nontemporal_load(&wrow[ks * 4 + h * 2 + 1]);
            cvt8(bf[ks], lo, hi);
        }
    }
    #pragma unroll
    for (int ks = 0; ks < 16; ks++)
        asm volatile("" : "+v"(bf[ks].q));    // keep resident (R5 lesson)

    // ---- bias for this thread's 4 col-groups: col0(q) = colwave + 8q + 4h ----
    f32x4 b4[4];
    #pragma unroll
    for (int q = 0; q < 4; q++) {
        int c0 = colwave + 8 * q + 4 * h;
        if (c0 + 4 > VOCAB) c0 = VOCAB - 4;   // clamp (aligned, mult of 4)
        b4[q] = *reinterpret_cast<const f32x4*>(bias + c0);
    }

    // ---- staging: R8 pattern (64 rows = 32KB, 8 x b128 per thread) ----
    u32x4 areg[8];
    auto load_chunk = [&](int c) {
        const u32x4* src = reinterpret_cast<const u32x4*>(Abf + (size_t)c * 64 * 256);
        #pragma unroll
        for (int i = 0; i < 8; i++) areg[i] = src[tid + i * 256];
    };
    auto write_lds = [&]() {
        #pragma unroll
        for (int i = 0; i < 8; i++) {
            int u = tid + i * 256;            // 0..2047 16B units
            int row = u >> 5, j = u & 31;
            int byte = row * 512 + ((j ^ (row & 7)) << 4);
            *reinterpret_cast<u32x4*>(&ldsA[byte]) = areg[i];
        }
    };

    load_chunk(0);

    for (int c = 0; c < mChunks; c++) {
        if (c > 0)                             // buf free: all reads of c-1 done
            asm volatile("s_barrier" ::: "memory");

        write_lds();                           // compiler waits vmcnt for areg
        asm volatile("s_waitcnt lgkmcnt(0)\n\ts_barrier" ::: "memory");

        if (c + 1 < mChunks) load_chunk(c + 1);   // hide under MFMAs

        f32x16 acc;
        #pragma unroll
        for (int i = 0; i < 16; i++) acc[i] = 0.0f;

        const int lrow = wr * 32 + cl;         // h1 local row this lane reads
        #pragma unroll
        for (int ks = 0; ks < 16; ks++) {
            const int jj = ks * 2 + h;
            const int byte = lrow * 512 + ((jj ^ (lrow & 7)) << 4);
            BFrag hb;
            hb.q = *reinterpret_cast<const u32x4*>(&ldsA[byte]);
            // SWAPPED: w_out as A-operand, h1 as B-operand
            acc = __builtin_amdgcn_mfma_f32_32x32x16_bf16(bf[ks].v, hb.v, acc, 0, 0, 0);
        }

        // epilogue: one batch row, 4 groups of 4 consecutive vocab cols
        const int grow = c * 64 + wr * 32 + cl;
        #pragma unroll
        for (int q = 0; q < 4; q++) {
            const int col0 = colwave + 8 * q + 4 * h;
            if (col0 + 4 <= VOCAB) {
                f32x4 v;
                #pragma unroll
                for (int j = 0; j < 4; j++)
                    v[j] = fast_tanh(acc[q * 4 + j] + b4[q][j]);
                *reinterpret_cast<f32x4*>(&C[(size_t)grow * VOCAB + col0]) = v;
            }
        }
    }
}

// K1: hproj = h0 @ w_hh^T  (512 x 768, K=256). R13/R14-proven small kernel.
__global__ __launch_bounds__(256, 4) void gemm_h(
    const float* __restrict__ A, const float* __restrict__ Bm,
    float* __restrict__ C)
{
    __shared__ char ldsA[16384];              // 32 rows x 256 bf16, swizzled

    const int tid  = threadIdx.x;
    const int wid  = tid >> 6;
    const int lane = tid & 63;
    const int r    = lane & 15;
    const int g    = lane >> 4;
    const int col  = blockIdx.x * 64 + wid * 16 + r;    // < 768 always
    const int mbase = blockIdx.y * 32;

    BFrag bf[8];
    {
        const f32x4* wrow = reinterpret_cast<const f32x4*>(Bm + (size_t)col * 256);
        #pragma unroll
        for (int kk = 0; kk < 8; kk++)
            cvt8(bf[kk], wrow[kk * 8 + g * 2], wrow[kk * 8 + g * 2 + 1]);
    }

    {
        const f32x4* src = reinterpret_cast<const f32x4*>(A + (size_t)mbase * 256);
        #pragma unroll
        for (int i = 0; i < 4; i++) {
            int u = tid + i * 256;
            int row = u >> 5, jj = u & 31;
            BFrag t; cvt8(t, src[2 * u], src[2 * u + 1]);
            int byte = row * 512 + ((jj ^ (row & 7)) << 4);
            *reinterpret_cast<u32x4*>(&ldsA[byte]) = t.q;
        }
    }
    __syncthreads();

    f32x4 acc0 = (f32x4){0.f, 0.f, 0.f, 0.f};
    f32x4 acc1 = (f32x4){0.f, 0.f, 0.f, 0.f};
    #pragma unroll
    for (int kk = 0; kk < 8; kk++) {
        const int s0 = r * 512 + ((((kk << 2) + g) ^ (r & 7)) << 4);
        BFrag a0, a1;
        a0.q = *reinterpret_cast<const u32x4*>(&ldsA[s0]);
        a1.q = *reinterpret_cast<const u32x4*>(&ldsA[s0 + 8192]);
        acc0 = __builtin_amdgcn_mfma_f32_16x16x32_bf16(a0.v, bf[kk].v, acc0, 0, 0, 0);
        acc1 = __builtin_amdgcn_mfma_f32_16x16x32_bf16(a1.v, bf[kk].v, acc1, 0, 0, 0);
    }

    const int rowb = mbase + g * 4;
    #pragma unroll
    for (int j = 0; j < 4; j++) {
        C[(size_t)(rowb + j) * GH + col]      = acc0[j];
        C[(size_t)(rowb + 16 + j) * GH + col] = acc1[j];
    }
}

// K2: GRU gates. One block per batch row, thread = k. Writes h1 (f32, d_out
// tail) and h1 bf16 row-major (K3's streamed operand).
__global__ __launch_bounds__(256) void gru_gate(
    const int* __restrict__ inp, const float* __restrict__ hidden,
    const float* __restrict__ w_ih, const float* __restrict__ b_ih,
    const float* __restrict__ b_hh, const float* __restrict__ hproj,
    float* __restrict__ h1out, unsigned short* __restrict__ h1bf)
{
    const int b = blockIdx.x;
    const int k = threadIdx.x;
    const int c = inp[b];

    float xr = w_ih[(size_t)k * VOCAB + c]         + b_ih[k];
    float xz = w_ih[(size_t)(k + 256) * VOCAB + c] + b_ih[k + 256];
    float xn = w_ih[(size_t)(k + 512) * VOCAB + c] + b_ih[k + 512];

    float hr = hproj[b * GH + k]       + b_hh[k];
    float hz = hproj[b * GH + 256 + k] + b_hh[k + 256];
    float hn = hproj[b * GH + 512 + k] + b_hh[k + 512];

    float rg = fast_sigmoid(xr + hr);
    float zg = fast_sigmoid(xz + hz);
    float ng = fast_tanh(xn + rg * hn);
    float h0 = hidden[b * HID + k];
    float h1 = (1.0f - zg) * ng + zg * h0;

    h1out[b * HID + k] = h1;
    __bf16 hb = (__bf16)h1;
    h1bf[b * HID + k] = __builtin_bit_cast(unsigned short, hb);
}

extern "C" void kernel_launch(void* const* d_in, const int* in_sizes, int n_in,
                              void* d_out, int out_size, void* d_ws, size_t ws_size,
                              hipStream_t stream) {
    const int*   input  = (const int*)  d_in[0];
    // d_in[1] = target (unused)
    const float* hidden = (const float*)d_in[2];
    const float* w_ih   = (const float*)d_in[3];
    const float* w_hh   = (const float*)d_in[4];
    const float* b_ih   = (const float*)d_in[5];
    const float* b_hh   = (const float*)d_in[6];
    const float* w_out  = (const float*)d_in[7];
    const float* b_out  = (const float*)d_in[8];

    float* logit = (float*)d_out;                            // [512, 50000]
    float* h1    = (float*)d_out + (size_t)BATCH * VOCAB;    // [512, 256]

    float*          hproj = (float*)d_ws;                                   // 1.5 MB
    unsigned short* h1bf  = (unsigned short*)((char*)d_ws + (size_t)BATCH * GH * 4);

    // K1: hproj = h0 @ w_hh^T — grid (12, 16)
    dim3 g1(GH / 64, BATCH / 32);
    gemm_h<<<g1, 256, 0, stream>>>(hidden, w_hh, hproj);

    // K2: gates -> h1 (f32) + h1bf (row-major bf16)
    gru_gate<<<BATCH, 256, 0, stream>>>(input, hidden, w_ih, b_ih, b_hh, hproj,
                                        h1, h1bf);

    // K3: logit = tanh(h1 @ w_out^T + b_out) — 782 col-tile blocks, 8 chunks
    dim3 g3((VOCAB + 63) / 64, 1);
    gemm_swp32<<<g3, 256, 0, stream>>>(h1bf, w_out, logit, b_out, 8);
}